// Round 1
// 648.248 us; speedup vs baseline: 1.1958x; 1.1958x over previous
//
#include <hip/hip_runtime.h>

// ---------- types ----------
typedef short short8 __attribute__((ext_vector_type(8)));
typedef float f32x4 __attribute__((ext_vector_type(4)));
typedef unsigned int u32x4 __attribute__((ext_vector_type(4)));
typedef unsigned short u16x4 __attribute__((ext_vector_type(4)));
typedef unsigned short u16x8 __attribute__((ext_vector_type(8)));

// ---------- bf16 helpers ----------
__device__ __forceinline__ unsigned short f2bf(float f) {
  unsigned int u = __builtin_bit_cast(unsigned int, f);
  u += 0x7fffu + ((u >> 16) & 1u);
  return (unsigned short)(u >> 16);
}
__device__ __forceinline__ float bf2f(unsigned short h) {
  unsigned int u = ((unsigned int)h) << 16;
  return __builtin_bit_cast(float, u);
}

// ---------- async global->LDS (16B per lane; LDS dst = wave base + lane*16) ----------
__device__ __forceinline__ void gl16(const unsigned short* g, unsigned short* l) {
  __builtin_amdgcn_global_load_lds((const __attribute__((address_space(1))) unsigned int*)g,
                                   (__attribute__((address_space(3))) unsigned int*)l, 16, 0, 0);
}

// ---------- problem constants ----------
#define BB 4
#define SS 2048
#define DD 2048
#define HH 16
#define HD 128
#define MM (BB * SS)  // 8192

// ---------- merged cast fp32 -> bf16 (x + 4 weights) ----------
__global__ void cast_all(const float* __restrict__ x, const float* __restrict__ wq,
                         const float* __restrict__ wk, const float* __restrict__ wv,
                         const float* __restrict__ wo, unsigned short* __restrict__ xb,
                         unsigned short* __restrict__ wqb, unsigned short* __restrict__ wkb,
                         unsigned short* __restrict__ wvb, unsigned short* __restrict__ wob) {
  int i = blockIdx.x * blockDim.x + threadIdx.x;
  const int X4 = (MM * DD) / 4;  // 4194304
  const int W4 = (DD * DD) / 4;  // 1048576
  const float* src;
  unsigned short* dst;
  int off;
  if (i < X4) {
    src = x; dst = xb; off = i;
  } else {
    int t = i - X4;
    int w = t >> 20;
    off = t & (W4 - 1);
    src = (w == 0) ? wq : (w == 1) ? wk : (w == 2) ? wv : wo;
    dst = (w == 0) ? wqb : (w == 1) ? wkb : (w == 2) ? wvb : wob;
  }
  f32x4 v = ((const f32x4*)src)[off];
  u16x4 o;
  o[0] = f2bf(v[0]); o[1] = f2bf(v[1]); o[2] = f2bf(v[2]); o[3] = f2bf(v[3]);
  ((u16x4*)dst)[off] = o;
}

// =====================================================================================
// 256x256 8-phase GEMM core (T2 swizzle + T3/T4 counted vmcnt + T5 setprio).
// C = A @ B^T, A: MxK row-major bf16, B: NxK row-major bf16, K = DD = 2048.
// 512 threads = 8 waves (2M x 4N); per-wave output 128x64; BK=64; NT=32 K-tiles.
// LDS 128 KiB: buf[t&1] holds K-tile t: A-tile 256x64 (16384 sh) + B-tile 256x64.
// Per 16B chunk at (row, c): stores global chunk c ^ (row&7)  (bank de-conflict).
// Schedule per tile t (4 phases): ph0 {ldA(qm0)+ldB(qn0), stage A0(t+1), mfma Q00},
// ph1 {ldB(qn1), stage A1(t+1), mfma Q01}, ph2 {ldA(qm1), stage B0(t+2), mfma Q11},
// ph3 {stage B1(t+2), mfma Q10, vmcnt(4) boundary}. Never vmcnt(0) except tail.
// =====================================================================================
#define STGH(P, R0, t, h, moff)                                                     \
  do {                                                                              \
    const unsigned short* _s =                                                      \
        (P) + (size_t)((R0) + (h) * 128 + srow) * DD + (size_t)((t) * 64 + scol);   \
    gl16(_s, lds + (moff) + (h) * 8192 + wvi * 512);                                \
    gl16(_s + (size_t)64 * DD, lds + (moff) + (h) * 8192 + 4096 + wvi * 512);       \
  } while (0)

#define BARRIER asm volatile("s_barrier" ::: "memory")

__device__ __forceinline__ void gemm_core(const unsigned short* __restrict__ Ap,
                                          const unsigned short* __restrict__ Bp,
                                          unsigned short* lds, int rt, int ct,
                                          f32x4 (&acc)[8][4]) {
  const int tid = threadIdx.x;
  const int lane = tid & 63, wvi = tid >> 6;
  const int wm = wvi >> 2, wn = wvi & 3;
  const int quad = lane >> 4, l16 = lane & 15;
  // staging decomposition: chunk u = c*512 + wvi*64 + lane; row = u>>3; src chunk xor
  const int srow = wvi * 8 + (lane >> 3);
  const int scol = ((lane & 7) ^ (lane >> 3)) << 3;
  // fragment-read swizzled chunk offsets (shorts): (k*4+quad) ^ (row&7), row&7 == l16&7
  const int ck0 = (quad ^ (l16 & 7)) << 3;
  const int ck1 = ((4 + quad) ^ (l16 & 7)) << 3;
  const int aro = (wm * 128 + l16) << 6;  // row base into A region (shorts)
  const int bro = (wn * 64 + l16) << 6;   // row base into B region (shorts)
  const int rb = rt * 256, cb = ct * 256;

#pragma unroll
  for (int i = 0; i < 8; ++i)
#pragma unroll
    for (int j = 0; j < 4; ++j) acc[i][j] = f32x4{0.f, 0.f, 0.f, 0.f};

  // ---- prologue: B(0), A(0), B(1); wait tile 0 (allow B(1)'s 4 loads outstanding)
  STGH(Bp, cb, 0, 0, 16384);
  STGH(Bp, cb, 0, 1, 16384);
  STGH(Ap, rb, 0, 0, 0);
  STGH(Ap, rb, 0, 1, 0);
  STGH(Bp, cb, 1, 0, 49152);
  STGH(Bp, cb, 1, 1, 49152);
  asm volatile("s_waitcnt vmcnt(4)" ::: "memory");
  BARRIER;

#pragma unroll 2
  for (int t = 0; t < 32; ++t) {
    const unsigned short* ab = lds + ((t & 1) << 15);
    const unsigned short* bb = ab + 16384;
    const int pn = ((t + 1) & 1) << 15;          // next buffer (A(t+1) dest)
    const int pc = ((t & 1) << 15) + 16384;      // current buffer B region (B(t+2) dest)
    short8 aq[4][2], b0f[2][2], b1f[2][2];

    // ---------- phase 0: quadrant (qm0,qn0) ----------
#pragma unroll
    for (int mi = 0; mi < 4; ++mi) {
      aq[mi][0] = __builtin_bit_cast(short8, *(const u32x4*)(ab + aro + mi * 1024 + ck0));
      aq[mi][1] = __builtin_bit_cast(short8, *(const u32x4*)(ab + aro + mi * 1024 + ck1));
    }
#pragma unroll
    for (int ni = 0; ni < 2; ++ni) {
      b0f[ni][0] = __builtin_bit_cast(short8, *(const u32x4*)(bb + bro + ni * 1024 + ck0));
      b0f[ni][1] = __builtin_bit_cast(short8, *(const u32x4*)(bb + bro + ni * 1024 + ck1));
    }
    if (t < 31) STGH(Ap, rb, t + 1, 0, pn);
    BARRIER;
    __builtin_amdgcn_s_setprio(1);
#pragma unroll
    for (int k = 0; k < 2; ++k)
#pragma unroll
      for (int mi = 0; mi < 4; ++mi)
#pragma unroll
        for (int ni = 0; ni < 2; ++ni)
          acc[mi][ni] =
              __builtin_amdgcn_mfma_f32_16x16x32_bf16(aq[mi][k], b0f[ni][k], acc[mi][ni], 0, 0, 0);
    __builtin_amdgcn_s_setprio(0);
    BARRIER;

    // ---------- phase 1: quadrant (qm0,qn1) ----------
#pragma unroll
    for (int ni = 0; ni < 2; ++ni) {
      b1f[ni][0] = __builtin_bit_cast(short8, *(const u32x4*)(bb + bro + 2048 + ni * 1024 + ck0));
      b1f[ni][1] = __builtin_bit_cast(short8, *(const u32x4*)(bb + bro + 2048 + ni * 1024 + ck1));
    }
    if (t < 31) STGH(Ap, rb, t + 1, 1, pn);
    BARRIER;
    __builtin_amdgcn_s_setprio(1);
#pragma unroll
    for (int k = 0; k < 2; ++k)
#pragma unroll
      for (int mi = 0; mi < 4; ++mi)
#pragma unroll
        for (int ni = 0; ni < 2; ++ni)
          acc[mi][2 + ni] = __builtin_amdgcn_mfma_f32_16x16x32_bf16(aq[mi][k], b1f[ni][k],
                                                                    acc[mi][2 + ni], 0, 0, 0);
    __builtin_amdgcn_s_setprio(0);
    BARRIER;

    // ---------- phase 2: quadrant (qm1,qn1) ----------
#pragma unroll
    for (int mi = 0; mi < 4; ++mi) {
      aq[mi][0] = __builtin_bit_cast(short8, *(const u32x4*)(ab + aro + 4096 + mi * 1024 + ck0));
      aq[mi][1] = __builtin_bit_cast(short8, *(const u32x4*)(ab + aro + 4096 + mi * 1024 + ck1));
    }
    if (t < 30) STGH(Bp, cb, t + 2, 0, pc);
    BARRIER;
    __builtin_amdgcn_s_setprio(1);
#pragma unroll
    for (int k = 0; k < 2; ++k)
#pragma unroll
      for (int mi = 0; mi < 4; ++mi)
#pragma unroll
        for (int ni = 0; ni < 2; ++ni)
          acc[4 + mi][2 + ni] = __builtin_amdgcn_mfma_f32_16x16x32_bf16(
              aq[mi][k], b1f[ni][k], acc[4 + mi][2 + ni], 0, 0, 0);
    __builtin_amdgcn_s_setprio(0);
    BARRIER;

    // ---------- phase 3: quadrant (qm1,qn0); boundary wait ----------
    if (t < 30) STGH(Bp, cb, t + 2, 1, pc);
    BARRIER;
    __builtin_amdgcn_s_setprio(1);
#pragma unroll
    for (int k = 0; k < 2; ++k)
#pragma unroll
      for (int mi = 0; mi < 4; ++mi)
#pragma unroll
        for (int ni = 0; ni < 2; ++ni)
          acc[4 + mi][ni] = __builtin_amdgcn_mfma_f32_16x16x32_bf16(aq[mi][k], b0f[ni][k],
                                                                    acc[4 + mi][ni], 0, 0, 0);
    __builtin_amdgcn_s_setprio(0);
    if (t < 30) {
      asm volatile("s_waitcnt vmcnt(4)" ::: "memory");  // tile t+1 landed; B(t+2) in flight
      BARRIER;
    } else if (t == 30) {
      asm volatile("s_waitcnt vmcnt(0)" ::: "memory");  // tail: drain A(31)
      BARRIER;
    }
  }
}

// ---------- QKV GEMM (merged): z=0 Q, z=1 K (chunk-XOR out-swizzle), z=2 V ----------
__global__ __launch_bounds__(512, 2) void gemm_qkv(const unsigned short* __restrict__ A,
                                                   const unsigned short* __restrict__ W0,
                                                   const unsigned short* __restrict__ W1,
                                                   const unsigned short* __restrict__ W2,
                                                   unsigned short* __restrict__ q_out,
                                                   unsigned short* __restrict__ k_out,
                                                   unsigned short* __restrict__ v_out) {
  __shared__ unsigned short lds[65536];
  const int ct = blockIdx.x, rt = blockIdx.y, z = blockIdx.z;
  const unsigned short* W = (z == 0) ? W0 : (z == 1) ? W1 : W2;
  unsigned short* outb = (z == 0) ? q_out : (z == 1) ? k_out : v_out;
  f32x4 acc[8][4];
  gemm_core(A, W, lds, rt, ct, acc);

  const int tid = threadIdx.x;
  const int lane = tid & 63, wvi = tid >> 6;
  const int wm = wvi >> 2, wn = wvi & 3;
  const int quad = lane >> 4, l16 = lane & 15;
#pragma unroll
  for (int mi = 0; mi < 8; ++mi)
#pragma unroll
    for (int ni = 0; ni < 4; ++ni)
#pragma unroll
      for (int r = 0; r < 4; ++r) {
        int row_g = rt * 256 + wm * 128 + mi * 16 + quad * 4 + r;
        int col_g = ct * 256 + wn * 64 + ni * 16 + l16;
        float v = acc[mi][ni][r];
        int b = row_g >> 11, s = row_g & (SS - 1);
        int h = col_g >> 7, d = col_g & (HD - 1);
        size_t rowbase = (((size_t)(b * HH + h)) * SS + (size_t)s) * HD;
        if (z == 1) {  // K: chunk-XOR swizzle (chunk = d>>3 XOR s&7) for attn staging
          outb[rowbase + (size_t)((((d >> 3) ^ (s & 7)) << 3) | (d & 7))] = f2bf(v);
        } else {  // Q, V standard
          outb[rowbase + (size_t)d] = f2bf(v);
        }
      }
}

// ---------- output GEMM: fp32 + bias ----------
__global__ __launch_bounds__(512, 2) void gemm_out(const unsigned short* __restrict__ A,
                                                   const unsigned short* __restrict__ W,
                                                   float* __restrict__ outf,
                                                   const float* __restrict__ bias) {
  __shared__ unsigned short lds[65536];
  const int ct = blockIdx.x, rt = blockIdx.y;
  f32x4 acc[8][4];
  gemm_core(A, W, lds, rt, ct, acc);

  const int tid = threadIdx.x;
  const int lane = tid & 63, wvi = tid >> 6;
  const int wm = wvi >> 2, wn = wvi & 3;
  const int quad = lane >> 4, l16 = lane & 15;
#pragma unroll
  for (int mi = 0; mi < 8; ++mi)
#pragma unroll
    for (int ni = 0; ni < 4; ++ni)
#pragma unroll
      for (int r = 0; r < 4; ++r) {
        int row_g = rt * 256 + wm * 128 + mi * 16 + quad * 4 + r;
        int col_g = ct * 256 + wn * 64 + ni * 16 + l16;
        outf[(size_t)row_g * DD + col_g] = acc[mi][ni][r] + bias[col_g];
      }
}

// ---------- RoPE: 4 pairs (16B) per thread; q pre-scaled by 1/sqrt(hd); k swizzle-aware ----------
__global__ void rope_kernel(unsigned short* __restrict__ qb, unsigned short* __restrict__ kb) {
  int id = blockIdx.x * blockDim.x + threadIdx.x;
  int c = id & 15;                 // logical chunk of 8 d-values
  int s = (id >> 4) & (SS - 1);
  int bhb = id >> 15;              // 0..127
  unsigned short* p;
  float psc;
  if (bhb < 64) {
    p = qb + ((size_t)bhb * SS + s) * HD + c * 8;
    psc = 0.08838834764831845f;    // fold softmax scale into q
  } else {
    p = kb + ((size_t)(bhb & 63) * SS + s) * HD + ((c ^ (s & 7)) << 3);
    psc = 1.0f;
  }
  u32x4 w = *(u32x4*)p;
  const float nl = -9.210340371976184f / 64.0f;  // -ln(10000)/64
  u32x4 o;
#pragma unroll
  for (int j = 0; j < 4; ++j) {
    int pi = c * 4 + j;
    float inv = __expf((float)pi * nl);
    float ang = (float)s * inv;
    float cs = __cosf(ang), sn = __sinf(ang);
    float e = bf2f((unsigned short)(w[j] & 0xffffu));
    float od = bf2f((unsigned short)(w[j] >> 16));
    float r1 = (e * cs - od * sn) * psc;
    float r2 = (e * sn + od * cs) * psc;
    o[j] = (unsigned int)f2bf(r1) | ((unsigned int)f2bf(r2) << 16);
  }
  *(u32x4*)p = o;
}

// ---------- Flash attention v4: occupancy-focused ----------
// 16 q-rows/wave, 64/block; kv-tile 64. K staged via gl16 (global pre-swizzled);
// V transposed in LDS (stride 72); P overlays Kt after QK (3rd barrier).
// LDS 34816 B -> 4 blocks/CU; VGPR<=128 -> 16 waves/CU.
// Grid 2048, bh-major (32 consecutive blocks share KV in L2), qa descending.
__global__ __launch_bounds__(256, 4) void attn_kernel(const unsigned short* __restrict__ qb,
                                                      const unsigned short* __restrict__ kb,
                                                      const unsigned short* __restrict__ vb,
                                                      unsigned short* __restrict__ ctxb) {
  __shared__ unsigned short Kt[64 * 128];  // swizzled K tile; P overlays after QK
  __shared__ unsigned short Vt[128 * 72];  // V^T [d][kv]
  const int tid = threadIdx.x;
  const int g = blockIdx.x;
  const int bh = g >> 5;             // 0..63
  const int qa = 31 - (g & 31);      // longest-first within bh
  const int lane = tid & 63, wvi = tid >> 6;
  const int quad = lane >> 4, l16 = lane & 15;
  const size_t bhq = (size_t)bh * SS * HD;
  const int qg = qa * 64;
  const int qrow = qg + wvi * 16;
  const int b = bh >> 4, h = bh & (HH - 1);
  unsigned short* Pw = Kt + wvi * 1024;  // 16x64 bf16 per wave (overlay)
  f32x4 zero = {0.f, 0.f, 0.f, 0.f};

  short8 qf[4];
#pragma unroll
  for (int ks = 0; ks < 4; ++ks)
    qf[ks] = __builtin_bit_cast(
        short8, *(const u32x4*)(qb + bhq + (size_t)(qrow + l16) * HD + ks * 32 + quad * 8));

  f32x4 acc[8];
#pragma unroll
  for (int dt = 0; dt < 8; ++dt) acc[dt] = zero;
  float lpart[4] = {0.f, 0.f, 0.f, 0.f};

  const int ntile = qa + 1;
  for (int kt = 0; kt < ntile; ++kt) {
    const int kv0 = kt * 64;
    __syncthreads();  // Kt(P)/Vt free from previous iteration
    // stage K via async DMA: 4 rounds x (4 rows/wave)
#pragma unroll
    for (int r = 0; r < 4; ++r)
      gl16(kb + bhq + (size_t)(kv0 + r * 16 + wvi * 4 + (lane >> 4)) * HD + (lane & 15) * 8,
           Kt + (r * 16 + wvi * 4) * 128);
    // stage V transposed [d][kv], stride 72, paired-u32 writes
    for (int u = tid; u < 512; u += 256) {
      int rr = u & 31, c = u >> 5;
      const unsigned short* vsrc = vb + bhq + (size_t)(kv0 + 2 * rr) * HD + c * 8;
      u16x8 va = __builtin_bit_cast(u16x8, *(const u32x4*)vsrc);
      u16x8 vb2 = __builtin_bit_cast(u16x8, *(const u32x4*)(vsrc + HD));
      unsigned int* vw = (unsigned int*)Vt;
#pragma unroll
      for (int j = 0; j < 8; ++j)
        vw[(c * 8 + j) * 36 + rr] = (unsigned int)va[j] | ((unsigned int)vb2[j] << 16);
    }
    __syncthreads();

    // QK^T: scores 16x64 per wave (kf XOR-unswizzle -> conflict-free)
    f32x4 sc[4];
#pragma unroll
    for (int nt = 0; nt < 4; ++nt) {
      sc[nt] = zero;
#pragma unroll
      for (int ks = 0; ks < 4; ++ks) {
        short8 kf = __builtin_bit_cast(
            short8, *(const u32x4*)(Kt + (nt * 16 + l16) * 128 +
                                    (((ks * 4 + quad) ^ (l16 & 7)) << 3)));
        sc[nt] = __builtin_amdgcn_mfma_f32_16x16x32_bf16(qf[ks], kf, sc[nt], 0, 0, 0);
      }
    }
    __syncthreads();  // all waves done reading Kt -> safe to overlay P

    // softmax (fixed max), P -> Kt overlay (XOR swizzle incl. prow>>3 term)
    const bool dm = (kt == ntile - 1);
    if (dm) {
#pragma unroll
      for (int r = 0; r < 4; ++r) {
        int row = qrow + quad * 4 + r;
        int prow = quad * 4 + r;
#pragma unroll
        for (int nt = 0; nt < 4; ++nt) {
          int col = nt * 16 + l16;
          float pv = (kv0 + col > row) ? 0.f : __expf(sc[nt][r]);
          lpart[r] += pv;
          int el = prow * 64 +
                   ((((nt * 2 + (l16 >> 3)) + prow + 4 * (prow >> 3)) & 7) << 3) + (l16 & 7);
          Pw[el] = f2bf(pv);
        }
      }
    } else {
#pragma unroll
      for (int r = 0; r < 4; ++r) {
        int prow = quad * 4 + r;
#pragma unroll
        for (int nt = 0; nt < 4; ++nt) {
          float pv = __expf(sc[nt][r]);
          lpart[r] += pv;
          int el = prow * 64 +
                   ((((nt * 2 + (l16 >> 3)) + prow + 4 * (prow >> 3)) & 7) << 3) + (l16 & 7);
          Pw[el] = f2bf(pv);
        }
      }
    }

    // PV: P(16x64) x V(64x128)
#pragma unroll
    for (int ks2 = 0; ks2 < 2; ++ks2) {
      short8 pf = __builtin_bit_cast(
          short8, *(const u32x4*)(Pw + l16 * 64 +
                                  ((((ks2 * 4 + quad) + l16 + 4 * (l16 >> 3)) & 7) << 3)));
#pragma unroll
      for (int dt = 0; dt < 8; ++dt) {
        short8 vf = __builtin_bit_cast(
            short8, *(const u32x4*)(Vt + (dt * 16 + l16) * 72 + ks2 * 32 + quad * 8));
        acc[dt] = __builtin_amdgcn_mfma_f32_16x16x32_bf16(pf, vf, acc[dt], 0, 0, 0);
      }
    }
  }

  // epilogue: one 16-lane reduction per row, ctx (B,S,D) bf16
  float rl[4];
#pragma unroll
  for (int r = 0; r < 4; ++r) {
    float rs = lpart[r];
#pragma unroll
    for (int off = 1; off < 16; off <<= 1) rs += __shfl_xor(rs, off, 64);
    rl[r] = 1.0f / rs;
  }
#pragma unroll
  for (int dt = 0; dt < 8; ++dt)
#pragma unroll
    for (int r = 0; r < 4; ++r) {
      int row = qrow + quad * 4 + r;
      ctxb[((size_t)(b * SS + row)) * DD + h * HD + dt * 16 + l16] = f2bf(acc[dt][r] * rl[r]);
    }
}

// ---------- launch ----------
extern "C" void kernel_launch(void* const* d_in, const int* in_sizes, int n_in,
                              void* d_out, int out_size, void* d_ws, size_t ws_size,
                              hipStream_t stream) {
  const float* x = (const float*)d_in[0];
  const float* wq = (const float*)d_in[1];
  const float* wk = (const float*)d_in[2];
  const float* wv = (const float*)d_in[3];
  const float* wo = (const float*)d_in[4];
  const float* bo = (const float*)d_in[5];
  float* out = (float*)d_out;

  unsigned short* xb = (unsigned short*)d_ws;
  unsigned short* wqb = xb + (size_t)MM * DD;
  unsigned short* wkb = wqb + (size_t)DD * DD;
  unsigned short* wvb = wkb + (size_t)DD * DD;
  unsigned short* wob = wvb + (size_t)DD * DD;
  unsigned short* qb = wob + (size_t)DD * DD;
  unsigned short* kb = qb + (size_t)MM * DD;
  unsigned short* vb = kb + (size_t)MM * DD;
  unsigned short* ctxb = vb + (size_t)MM * DD;

  cast_all<<<(2 * MM * DD / 4) / 256, 256, 0, stream>>>(x, wq, wk, wv, wo, xb, wqb, wkb, wvb, wob);

  dim3 gg(DD / 256, MM / 256, 3);
  gemm_qkv<<<gg, 512, 0, stream>>>(xb, wqb, wkb, wvb, qb, kb, vb);

  rope_kernel<<<(128 * 2048 * 16) / 256, 256, 0, stream>>>(qb, kb);

  attn_kernel<<<2048, 256, 0, stream>>>(qb, kb, vb, ctxb);

  dim3 go(DD / 256, MM / 256);
  gemm_out<<<go, 512, 0, stream>>>(ctxb, wob, out, bo);
}